// Round 11
// baseline (328.100 us; speedup 1.0000x reference)
//
#include <hip/hip_runtime.h>
#include <math.h>

typedef __attribute__((ext_vector_type(4))) float f32x4;
typedef __attribute__((ext_vector_type(8))) short sh8;

__device__ __forceinline__ float bf2f(unsigned short u){
    union { unsigned int i; float f; } v; v.i = ((unsigned)u) << 16; return v.f;
}
__device__ __forceinline__ unsigned short f2bf(float f){
    union { float f; unsigned int i; } v; v.f = f;
    unsigned int x = v.i;
    x += 0x7fff + ((x >> 16) & 1);   // RNE; inputs finite
    return (unsigned short)(x >> 16);
}

// ---------------------------------------------------------------------------
// Merged weight transform conv2..conv8:
// w [COUT][CIN][3][3] fp32 -> wT [tap][COUT][CIN] bf16 (RNE)
// ---------------------------------------------------------------------------
struct WTArgs {
    const float* src[7];
    unsigned short* hi[7];
    int cin[7];
    int start[8];
};

__global__ void wtrans_all(WTArgs a)
{
    int e = blockIdx.x * 256 + threadIdx.x;
    if (e >= a.start[7]) return;
    int l = 0;
    while (e >= a.start[l + 1]) l++;
    int eL = e - a.start[l];
    int CIN = a.cin[l];
    int tap = eL % 9, rest = eL / 9;
    int ci = rest % CIN, co = rest / CIN;
    int COUT = (a.start[l + 1] - a.start[l]) / (9 * CIN);
    a.hi[l][(tap * COUT + co) * CIN + ci] = f2bf(a.src[l][eL]);
}

// ---------------------------------------------------------------------------
// conv1: Cin=2 fp32 direct conv + BN + ReLU -> NHWC bf16 (full batch)
// ---------------------------------------------------------------------------
__global__ __launch_bounds__(256) void conv1_kernel(
    const float* __restrict__ in, const float* __restrict__ w,
    const float* __restrict__ cb, const float* __restrict__ sc,
    const float* __restrict__ tb, unsigned short* __restrict__ out)
{
    __shared__ float s_w[18 * 64];
    __shared__ float s_in[2][18 * 20];

    const int tid = threadIdx.x;
    const int b = blockIdx.y;
    const int tile = blockIdx.x;
    const int ty = tile >> 3, tx = tile & 7;
    const int y0 = ty * 16, x0 = tx * 16;

    for (int idx = tid; idx < 1152; idx += 256) {
        int co = idx & 63, kk2 = idx >> 6;
        s_w[kk2 * 64 + co] = w[co * 18 + kk2];
    }
    for (int idx = tid; idx < 2 * 324; idx += 256) {
        int ci = idx / 324, rem = idx % 324;
        int r = rem / 18, c = rem % 18;
        int gy = y0 + r - 1, gx = x0 + c - 1;
        float v = 0.f;
        if (gy >= 0 && gy < 128 && gx >= 0 && gx < 128)
            v = in[((size_t)(b * 2 + ci) * 128 + gy) * 128 + gx];
        s_in[ci][r * 20 + c] = v;
    }
    __syncthreads();

    const int cog = tid >> 5;
    const int slot = tid & 31;
    const int sy = slot >> 2, sx = slot & 3;

    float p[2][4][6];
#pragma unroll
    for (int ci = 0; ci < 2; ci++)
#pragma unroll
        for (int r = 0; r < 4; r++)
#pragma unroll
            for (int c = 0; c < 6; c++)
                p[ci][r][c] = s_in[ci][(2 * sy + r) * 20 + 4 * sx + c];

    float acc[2][4][8];
#pragma unroll
    for (int r = 0; r < 2; r++)
#pragma unroll
        for (int c = 0; c < 4; c++)
#pragma unroll
            for (int o = 0; o < 8; o++) acc[r][c][o] = 0.f;

#pragma unroll
    for (int kk2 = 0; kk2 < 18; kk2++) {
        const int ci = kk2 / 9, k = kk2 % 9;
        const int ky = k / 3, kx = k % 3;
        float wv[8];
#pragma unroll
        for (int q = 0; q < 2; q++) {
            f32x4 w4 = *(const f32x4*)(&s_w[kk2 * 64 + cog * 8 + q * 4]);
#pragma unroll
            for (int z = 0; z < 4; z++) wv[q * 4 + z] = w4[z];
        }
#pragma unroll
        for (int r = 0; r < 2; r++)
#pragma unroll
            for (int c = 0; c < 4; c++) {
                float pv = p[ci][r + ky][c + kx];
#pragma unroll
                for (int o = 0; o < 8; o++) acc[r][c][o] += pv * wv[o];
            }
    }

    float bb[8], ss[8], tt[8];
#pragma unroll
    for (int o = 0; o < 8; o++) { bb[o] = cb[cog*8+o]; ss[o] = sc[cog*8+o]; tt[o] = tb[cog*8+o]; }
#pragma unroll
    for (int r = 0; r < 2; r++)
#pragma unroll
        for (int c = 0; c < 4; c++) {
            unsigned short ov[8];
#pragma unroll
            for (int o = 0; o < 8; o++)
                ov[o] = f2bf(fmaxf((acc[r][c][o] + bb[o]) * ss[o] + tt[o], 0.f));
            int py = y0 + 2 * sy + r, px = x0 + 4 * sx + c;
            *(sh8*)(out + ((size_t)(b * 128 + py) * 128 + px) * 64 + cog * 8) = *(sh8*)ov;
        }
}

// ---------------------------------------------------------------------------
// MFMA implicit-GEMM conv3x3 + BN + ReLU (+ fused 2x2 maxpool), v8:
// round-10 v6 structure with T4-style counted-wait pipeline:
//  - W reg-ring rwA/rwB, loads issued 3 taps ahead (taps 0-2 in prologue)
//  - per tap: WRITEW(t+1, other slot); issue load(t+3); ds_read frags;
//    s_waitcnt lgkmcnt(0); RAW s_barrier (no vmcnt drain); MFMA.
//  One barrier/tap, zero drains, ~2-tap global-latency cover.
// ---------------------------------------------------------------------------
template<int CIN, int COUT, int HI, int WI, int POOL, int TW, int NPG, int KSPLIT>
__global__ __launch_bounds__(NPG * 128, 4) void conv_mfma(
    const unsigned short* __restrict__ in,
    const unsigned short* __restrict__ wgt,
    const float* __restrict__ cb, const float* __restrict__ sc,
    const float* __restrict__ tb, void* __restrict__ outv)
{
    constexpr int THREADS = NPG * 128;
    constexpr int TH = (TW == 32) ? 2 * NPG : 4 * NPG;
    constexpr int HALW = TW + 2, HALH = TH + 2;
    constexpr int NPIX = HALW * HALH;
    constexpr int CHUNKS = CIN / 64;
    constexpr int TILESX = WI / TW;
    constexpr int HO = HI / POOL, WO = WI / POOL;
    constexpr int ST = 68;
    constexpr int NCOG = COUT / 64;
    constexpr int GPT = 512 / THREADS;
    constexpr int LOG_NPG = (NPG == 4) ? 2 : 1;

    __shared__ __align__(16) unsigned short lds_A[NPIX * ST];
    __shared__ __align__(16) unsigned short lds_W[2][4096];

    const int tid = threadIdx.x;
    const int lane = tid & 63;
    const int i = lane & 15, j = lane >> 4;
    const int wv = tid >> 6;
    const int pg = wv & (NPG - 1);
    const int cg = wv >> LOG_NPG;
    const int tile = blockIdx.x;
    const int ty = tile / TILESX, tx = tile % TILESX;
    const int y0 = ty * TH, x0 = tx * TW;
    const int cogrp = (NCOG == 1) ? 0 : (blockIdx.y & (NCOG - 1));
    const int kc = (KSPLIT == 2) ? (blockIdx.y >> (NCOG == 2 ? 1 : 0)) : 0;
    const int coBase = cogrp * 64;
    const int b = blockIdx.z;

    f32x4 acc[4][2];
#pragma unroll
    for (int pf = 0; pf < 4; pf++)
#pragma unroll
        for (int cf = 0; cf < 2; cf++) acc[pf][cf] = (f32x4){0.f, 0.f, 0.f, 0.f};

    sh8 rwA[GPT], rwB[GPT];   // W ring: even taps in A, odd taps in B

    auto LOADW = [&](sh8 (&dst)[GPT], int c, int tap) {
#pragma unroll
        for (int q = 0; q < GPT; q++) {
            int g = tid + q * THREADS;
            int slot = g & 7;
            int co = g >> 3;
            int gl = slot ^ (co & 7);
            dst[q] = *(const sh8*)(wgt + ((size_t)(tap * COUT + coBase + co)) * CIN
                                  + c * 64 + gl * 8);
        }
    };
    auto WRITEW = [&](int bi, sh8 (&src)[GPT]) {
#pragma unroll
        for (int q = 0; q < GPT; q++)
            *(sh8*)(&lds_W[bi][(tid + q * THREADS) * 8]) = src[q];
    };

    constexpr int NCH = (KSPLIT == 2) ? 1 : CHUNKS;
    for (int cc = 0; cc < NCH; cc++) {
        const int c = (KSPLIT == 2) ? kc : cc;
        if (cc) {   // protect lds_A / slot reuse across chunks
            asm volatile("s_waitcnt lgkmcnt(0)" ::: "memory");
            __builtin_amdgcn_s_barrier();
        }

        // ---- stage A halo: NPIX px x 64 cin, zero-padded ----
        for (int u = tid; u < NPIX * 8; u += THREADS) {
            int hp = u >> 3, c16 = u & 7;
            int hy = hp / HALW, hx = hp % HALW;
            int gy = y0 + hy - 1, gx = x0 + hx - 1;
            sh8 v = (sh8){0,0,0,0,0,0,0,0};
            if (gy >= 0 && gy < HI && gx >= 0 && gx < WI)
                v = *(const sh8*)(in + ((size_t)(b * HI + gy) * WI + gx) * CIN + c * 64 + c16 * 8);
            *(sh8*)(&lds_A[hp * ST + c16 * 8]) = v;
        }

        // ---- W pipeline prologue: taps 0,1 loaded; tap0 -> slot0; tap2 issued ----
        LOADW(rwA, c, 0);
        LOADW(rwB, c, 1);
        WRITEW(0, rwA);          // counted vmcnt wait on tap0's loads only
        LOADW(rwA, c, 2);        // rwA freed at WRITEW issue
        asm volatile("s_waitcnt lgkmcnt(0)" ::: "memory");
        __builtin_amdgcn_s_barrier();

#pragma unroll
        for (int tap = 0; tap < 9; tap++) {
            const int ky = tap / 3, kx = tap % 3;
            const int bi = tap & 1;
            // stage next tap's W into the other slot (data loaded 2 taps ago)
            if (tap < 8) {
                if (bi == 0) WRITEW(1, rwB); else WRITEW(0, rwA);
            }
            // issue global load 3 taps ahead into the reg just consumed
            if (tap <= 5) {
                if (bi == 0) LOADW(rwB, c, tap + 3); else LOADW(rwA, c, tap + 3);
            }
            // ds_read fragments for this tap
            sh8 aF[4], bF[2];
#pragma unroll
            for (int kk = 0; kk < 2; kk++) {
#pragma unroll
                for (int pf = 0; pf < 4; pf++) {
                    if (kk == 1) continue;
                }
            }
#pragma unroll
            for (int pf = 0; pf < 4; pf++) {
                const int nf = pg * 4 + pf;
                int hy2, hx2;
                if (TW == 32) { hy2 = (nf >> 1) + ky; hx2 = (nf & 1) * 16 + i + kx; }
                else          { hy2 = nf + ky;        hx2 = i + kx; }
                aF[pf] = *(const sh8*)(&lds_A[(hy2 * HALW + hx2) * ST + 0 * 32 + j * 8]);
            }
#pragma unroll
            for (int cf = 0; cf < 2; cf++) {
                const int co_l = cg * 32 + cf * 16 + i;
                const int phys = ((0 << 2) | j) ^ (co_l & 7);
                bF[cf] = *(const sh8*)(&lds_W[bi][(co_l * 8 + phys) * 8]);
            }
            sh8 aF2[4], bF2[2];
#pragma unroll
            for (int pf = 0; pf < 4; pf++) {
                const int nf = pg * 4 + pf;
                int hy2, hx2;
                if (TW == 32) { hy2 = (nf >> 1) + ky; hx2 = (nf & 1) * 16 + i + kx; }
                else          { hy2 = nf + ky;        hx2 = i + kx; }
                aF2[pf] = *(const sh8*)(&lds_A[(hy2 * HALW + hx2) * ST + 1 * 32 + j * 8]);
            }
#pragma unroll
            for (int cf = 0; cf < 2; cf++) {
                const int co_l = cg * 32 + cf * 16 + i;
                const int phys = ((1 << 2) | j) ^ (co_l & 7);
                bF2[cf] = *(const sh8*)(&lds_W[bi][(co_l * 8 + phys) * 8]);
            }
            // reads landed -> raw barrier (NO vmcnt drain: W loads stay in flight)
            asm volatile("s_waitcnt lgkmcnt(0)" ::: "memory");
            if (tap < 8 || cc + 1 < NCH) __builtin_amdgcn_s_barrier();

            __builtin_amdgcn_s_setprio(1);
#pragma unroll
            for (int pf = 0; pf < 4; pf++)
#pragma unroll
                for (int cf = 0; cf < 2; cf++)
                    acc[pf][cf] = __builtin_amdgcn_mfma_f32_16x16x32_bf16(
                        aF[pf], bF[cf], acc[pf][cf], 0, 0, 0);
#pragma unroll
            for (int pf = 0; pf < 4; pf++)
#pragma unroll
                for (int cf = 0; cf < 2; cf++)
                    acc[pf][cf] = __builtin_amdgcn_mfma_f32_16x16x32_bf16(
                        aF2[pf], bF2[cf], acc[pf][cf], 0, 0, 0);
            __builtin_amdgcn_s_setprio(0);
        }
    }

    if constexpr (KSPLIT == 2) {
        float* po = (float*)outv + (size_t)kc * 64 * HO * WO * COUT;
#pragma unroll
        for (int cf = 0; cf < 2; cf++) {
            const int co = coBase + cg * 32 + cf * 16 + i;
#pragma unroll
            for (int pf = 0; pf < 4; pf++) {
                const int nf = pg * 4 + pf;
                int py, pxb;
                if (TW == 32) { py = nf >> 1; pxb = (nf & 1) * 16; }
                else          { py = nf;      pxb = 0; }
#pragma unroll
                for (int r = 0; r < 4; r++)
                    po[((size_t)(b * HO + y0 + py) * WO + x0 + pxb + j * 4 + r) * COUT + co] =
                        acc[pf][cf][r];
            }
        }
        return;
    }

    unsigned short* out = (unsigned short*)outv;
#pragma unroll
    for (int cf = 0; cf < 2; cf++) {
        const int co = coBase + cg * 32 + cf * 16 + i;
        const float b3 = cb[co], s3 = sc[co], t3 = tb[co];
        if (POOL == 1) {
#pragma unroll
            for (int pf = 0; pf < 4; pf++) {
                const int nf = pg * 4 + pf;
                int py, pxb;
                if (TW == 32) { py = nf >> 1; pxb = (nf & 1) * 16; }
                else          { py = nf;      pxb = 0; }
#pragma unroll
                for (int r = 0; r < 4; r++) {
                    float v = fmaxf((acc[pf][cf][r] + b3) * s3 + t3, 0.f);
                    out[((size_t)(b * HO + y0 + py) * WO + x0 + pxb + j * 4 + r) * COUT + co] = f2bf(v);
                }
            }
        } else if constexpr (POOL == 2 && TW == 32) {
#pragma unroll
            for (int h = 0; h < 2; h++) {
                const int pfA = h, pfB = 2 + h;
#pragma unroll
                for (int r2 = 0; r2 < 2; r2++) {
                    float vA0 = fmaxf((acc[pfA][cf][2*r2]   + b3) * s3 + t3, 0.f);
                    float vA1 = fmaxf((acc[pfA][cf][2*r2+1] + b3) * s3 + t3, 0.f);
                    float vB0 = fmaxf((acc[pfB][cf][2*r2]   + b3) * s3 + t3, 0.f);
                    float vB1 = fmaxf((acc[pfB][cf][2*r2+1] + b3) * s3 + t3, 0.f);
                    float v = fmaxf(fmaxf(vA0, vA1), fmaxf(vB0, vB1));
                    int pox = (x0 >> 1) + h * 8 + j * 2 + r2;
                    int poy = (y0 >> 1) + pg;
                    out[((size_t)(b * HO + poy) * WO + pox) * COUT + co] = f2bf(v);
                }
            }
        }
    }
}

// ---------------------------------------------------------------------------
// split-K combine
// ---------------------------------------------------------------------------
__global__ void combine_k(const float* __restrict__ part, const float* __restrict__ cb,
                          const float* __restrict__ sc, const float* __restrict__ tb,
                          unsigned short* __restrict__ out)
{
    int e = blockIdx.x * 256 + threadIdx.x;
    int co = e & 127;
    float v = part[e] + part[e + 2097152];
    out[e] = f2bf(fmaxf((v + cb[co]) * sc[co] + tb[co], 0.f));
}

// ---------------------------------------------------------------------------
// 6x6/6 maxpool
// ---------------------------------------------------------------------------
__global__ void pool6_kernel(const unsigned short* __restrict__ in, float* __restrict__ out)
{
    int t = blockIdx.x * 256 + threadIdx.x;
    if (t >= 64 * 128 * 4) return;
    int ox = t & 1, oy = (t >> 1) & 1, c = (t >> 2) & 127, b = t >> 9;
    const unsigned short* p = in + ((size_t)(b * 16 + oy * 6) * 16 + ox * 6) * 128 + c;
    float m = -INFINITY;
#pragma unroll
    for (int r = 0; r < 6; r++)
#pragma unroll
        for (int cc = 0; cc < 6; cc++) m = fmaxf(m, bf2f(p[(r * 16 + cc) * 128]));
    out[(size_t)b * 512 + c * 4 + oy * 2 + ox] = m;
}

// ---------------------------------------------------------------------------
// FC1 / FC2
// ---------------------------------------------------------------------------
__global__ void fc1_kernel(const float* __restrict__ flat, const float* __restrict__ fcw,
                           const float* __restrict__ fcb, float* __restrict__ out1)
{
    int b = blockIdx.y;
    int jj = blockIdx.x * 256 + threadIdx.x;
    const f32x4* f = (const f32x4*)(flat + (size_t)b * 512);
    const f32x4* w = (const f32x4*)(fcw + (size_t)jj * 512);
    float s = fcb[jj];
    for (int k = 0; k < 128; k++) {
        f32x4 a = f[k], ww = w[k];
        s += a[0]*ww[0] + a[1]*ww[1] + a[2]*ww[2] + a[3]*ww[3];
    }
    out1[(size_t)b * 1024 + jj] = fmaxf(s, 0.f);
}

__global__ void fc2_kernel(const float* __restrict__ out1, const float* __restrict__ f1w,
                           const float* __restrict__ f1b, float* __restrict__ h4pt)
{
    int b = blockIdx.x;
    int o = threadIdx.x >> 5, s2 = threadIdx.x & 31;
    const float* pa = out1 + (size_t)b * 1024;
    const float* pw = f1w + (size_t)o * 1024;
    float s = 0.f;
    for (int k = s2; k < 1024; k += 32) s += pa[k] * pw[k];
#pragma unroll
    for (int m = 16; m; m >>= 1) s += __shfl_xor(s, m);
    if (s2 == 0) h4pt[b * 8 + o] = s + f1b[o];
}

// ---------------------------------------------------------------------------
// DLT v2: row-per-lane fp64 Gauss elimination with partial pivoting (proven).
// ---------------------------------------------------------------------------
__global__ __launch_bounds__(512) void dlt_kernel(
    const float* __restrict__ h4pt, const float* __restrict__ corner,
    double* __restrict__ hinv)
{
    const int t = threadIdx.x;
    const int lane = t & 63;
    const int r = lane & 7;
    const int base = lane & ~7;
    const int b = (t >> 6) * 8 + (lane >> 3);

    const int jq = r >> 1;
    const double U  = (double)corner[b * 8 + 2 * jq];
    const double V  = (double)corner[b * 8 + 2 * jq + 1];
    const double Ud = U + (double)h4pt[b * 8 + 2 * jq];
    const double Vd = V + (double)h4pt[b * 8 + 2 * jq + 1];

    double Ar[9];
    if ((r & 1) == 0) {
        Ar[0] = 0;  Ar[1] = 0;  Ar[2] = 0;
        Ar[3] = -U; Ar[4] = V;  Ar[5] = -1;
        Ar[6] = Vd * U; Ar[7] = Vd * V; Ar[8] = -Vd;
    } else {
        Ar[0] = U;  Ar[1] = V;  Ar[2] = 1;
        Ar[3] = 0;  Ar[4] = 0;  Ar[5] = 0;
        Ar[6] = -Ud * U; Ar[7] = -Ud * V; Ar[8] = Ud;
    }

#pragma unroll
    for (int col = 0; col < 8; col++) {
        double val = (r >= col) ? fabs(Ar[col]) : -1.0;
        int idx = r;
#pragma unroll
        for (int m = 1; m < 8; m <<= 1) {
            double ov = __shfl_xor(val, m, 64);
            int oi = __shfl_xor(idx, m, 64);
            if (ov > val || (ov == val && oi < idx)) { val = ov; idx = oi; }
        }
        const int src = (r == col) ? idx : (r == idx) ? col : r;
#pragma unroll
        for (int k = 0; k < 9; k++) Ar[k] = __shfl(Ar[k], base + src, 64);
        double pr[9];
#pragma unroll
        for (int k = 0; k < 9; k++) pr[k] = __shfl(Ar[k], base + col, 64);
        if (r > col) {
            const double f = Ar[col] / pr[col];
#pragma unroll
            for (int k = 0; k < 9; k++) Ar[k] -= f * pr[k];
        }
    }

    double h[9];
    h[8] = 1.0;
#pragma unroll
    for (int col = 7; col >= 0; col--) {
        const double xc = __shfl(Ar[8] / Ar[col], base + col, 64);
        h[col] = xc;
        if (r < col) Ar[8] -= Ar[col] * xc;
    }

    const double a = h[0], bb = h[1], cq = h[2], d = h[3], e = h[4],
                 f = h[5], g = h[6], hh = h[7], iq = h[8];
    const double C0 = e * iq - f * hh, C1 = cq * hh - bb * iq, C2 = bb * f - cq * e;
    const double C3 = f * g - d * iq,  C4 = a * iq - cq * g,   C5 = cq * d - a * f;
    const double C6 = d * hh - e * g,  C7 = bb * g - a * hh,   C8 = a * e - bb * d;
    const double det = a * C0 + bb * C3 + cq * C6;
    const double idet = 1.0 / det;
    double my = (r == 0) ? C0 : (r == 1) ? C1 : (r == 2) ? C2 : (r == 3) ? C3
              : (r == 4) ? C4 : (r == 5) ? C5 : (r == 6) ? C6 : C7;
    double* o = hinv + b * 9;
    o[r] = my * idet;
    if (r == 0) o[8] = C8 * idet;
}

// ---------------------------------------------------------------------------
// Perspective warp + bilinear (coords fp64, gather fp32)
// ---------------------------------------------------------------------------
__global__ void warp_kernel(const float* __restrict__ img, const double* __restrict__ hinv,
                            float* __restrict__ out)
{
    int b = blockIdx.y;
    int pix = blockIdx.x * 256 + threadIdx.x;
    int y = pix >> 7, x = pix & 127;
    const double* h = hinv + b * 9;
    double X = (double)x, Y = (double)y;
    double p0 = h[0] * X + h[1] * Y + h[2];
    double p1 = h[3] * X + h[4] * Y + h[5];
    double p2 = h[6] * X + h[7] * Y + h[8];
    double xs = p0 / p2, ys = p1 / p2;
    double x0d = floor(xs), y0d = floor(ys);
    double wx = xs - x0d, wy = ys - y0d;
    int x0 = (int)x0d, y0 = (int)y0d;
    const float* im = img + (size_t)b * 240 * 320;
    auto gat = [&](int yi, int xi) -> double {
        bool valid = (xi >= 0) & (xi < 320) & (yi >= 0) & (yi < 240);
        int yc = yi < 0 ? 0 : (yi > 239 ? 239 : yi);
        int xc = xi < 0 ? 0 : (xi > 319 ? 319 : xi);
        double v = (double)im[yc * 320 + xc];
        return valid ? v : 0.0;
    };
    double v00 = gat(y0, x0),     v01 = gat(y0, x0 + 1);
    double v10 = gat(y0 + 1, x0), v11 = gat(y0 + 1, x0 + 1);
    double rr = v00 * (1 - wx) * (1 - wy) + v01 * wx * (1 - wy)
              + v10 * (1 - wx) * wy       + v11 * wx * wy;
    out[((size_t)b << 14) + pix] = (float)rr;
}

// ---------------------------------------------------------------------------
// launch — full-batch, no chunking.
// Layout: A1 134.2 MB | B2 33.5 MB | weights 1.25 MB | small.  Total ~170 MB.
// ---------------------------------------------------------------------------
extern "C" void kernel_launch(void* const* d_in, const int* in_sizes, int n_in,
                              void* d_out, int out_size, void* d_ws, size_t ws_size,
                              hipStream_t stream)
{
    const float* TI1     = (const float*)d_in[1];
    const float* TImgA   = (const float*)d_in[2];
    const float* TCorner = (const float*)d_in[3];
    const float* w[8], *cbp[8], *sp[8], *tp[8];
    for (int l = 0; l < 8; l++) {
        w[l]   = (const float*)d_in[4 + 4 * l];
        cbp[l] = (const float*)d_in[5 + 4 * l];
        sp[l]  = (const float*)d_in[6 + 4 * l];
        tp[l]  = (const float*)d_in[7 + 4 * l];
    }
    const float* fcw = (const float*)d_in[36];
    const float* fcb = (const float*)d_in[37];
    const float* f1w = (const float*)d_in[38];
    const float* f1b = (const float*)d_in[39];

    char* base = (char*)d_ws;
    unsigned short* A1   = (unsigned short*)(base);                   // 134,217,728 B
    unsigned short* B2   = (unsigned short*)(base + 134217728);       // 33,554,432 B
    unsigned short* whiA = (unsigned short*)(base + 167772160);       // 1,253,376 B
    float*  feat = (float*) (base + 167772160 + 1253376);
    float*  fc1o = feat + 64 * 512;
    float*  h4pt = fc1o + 64 * 1024;
    double* hinv = (double*)(h4pt + 512);
    float*  outp = (float*)d_out;

    // conv7/8 split-K sub-regions (A1 free as scratch after conv5)
    float*          part7 = (float*)A1;                               // 16.8 MB
    unsigned short* c7out = (unsigned short*)(base + 134217728 + 8388608);   // B2+8MB
    float*          part8 = (float*)A1;
    unsigned short* c8out = (unsigned short*)(base + 134217728 + 16777216);  // B2+16MB

    const int CINS[7]  = {64, 64, 64, 64, 128, 128, 128};
    const int COUTS[7] = {64, 64, 64, 128, 128, 128, 128};
    int wofs[8]; wofs[0] = 0;
    for (int l = 0; l < 7; l++) wofs[l + 1] = wofs[l] + 9 * COUTS[l] * CINS[l];

    WTArgs wa;
    for (int l = 0; l < 7; l++) {
        wa.src[l] = w[l + 1];
        wa.hi[l] = whiA + wofs[l];
        wa.cin[l] = CINS[l];
        wa.start[l] = wofs[l];
    }
    wa.start[7] = wofs[7];
    wtrans_all<<<(wofs[7] + 255) / 256, 256, 0, stream>>>(wa);

    // conv1 full batch -> A1 ; conv2 full batch -> B2
    conv1_kernel<<<dim3(64, 64), 256, 0, stream>>>(
        TI1, w[0], cbp[0], sp[0], tp[0], A1);
    conv_mfma<64, 64, 128, 128, 2, 32, 4, 1><<<dim3(64, 1, 64), 512, 0, stream>>>(
        A1, whiA + wofs[0], cbp[1], sp[1], tp[1], B2);
    // conv3..conv6, ping-pong B2 <-> A1
    conv_mfma<64, 64, 64, 64, 1, 32, 4, 1><<<dim3(16, 1, 64), 512, 0, stream>>>(
        B2, whiA + wofs[1], cbp[2], sp[2], tp[2], A1);
    conv_mfma<64, 64, 64, 64, 2, 32, 4, 1><<<dim3(16, 1, 64), 512, 0, stream>>>(
        A1, whiA + wofs[2], cbp[3], sp[3], tp[3], B2);
    conv_mfma<64, 128, 32, 32, 1, 32, 4, 1><<<dim3(4, 2, 64), 512, 0, stream>>>(
        B2, whiA + wofs[3], cbp[4], sp[4], tp[4], A1);
    conv_mfma<128, 128, 32, 32, 2, 32, 4, 1><<<dim3(4, 2, 64), 512, 0, stream>>>(
        A1, whiA + wofs[4], cbp[5], sp[5], tp[5], B2);
    // conv7/8: split-K over cin halves -> fp32 partials in A1 -> combine
    conv_mfma<128, 128, 16, 16, 1, 16, 2, 2><<<dim3(2, 4, 64), 256, 0, stream>>>(
        B2, whiA + wofs[5], cbp[6], sp[6], tp[6], part7);
    combine_k<<<8192, 256, 0, stream>>>(part7, cbp[6], sp[6], tp[6], c7out);
    conv_mfma<128, 128, 16, 16, 1, 16, 2, 2><<<dim3(2, 4, 64), 256, 0, stream>>>(
        c7out, whiA + wofs[6], cbp[7], sp[7], tp[7], part8);
    combine_k<<<8192, 256, 0, stream>>>(part8, cbp[7], sp[7], tp[7], c8out);

    pool6_kernel<<<128, 256, 0, stream>>>(c8out, feat);
    fc1_kernel<<<dim3(4, 64), 256, 0, stream>>>(feat, fcw, fcb, fc1o);
    fc2_kernel<<<64, 256, 0, stream>>>(fc1o, f1w, f1b, h4pt);
    dlt_kernel<<<1, 512, 0, stream>>>(h4pt, TCorner, hinv);
    warp_kernel<<<dim3(64, 64), 256, 0, stream>>>(TImgA, hinv, outp);
}

// Round 12
// 317.993 us; speedup vs baseline: 1.0318x; 1.0318x over previous
//
#include <hip/hip_runtime.h>
#include <math.h>

typedef __attribute__((ext_vector_type(4))) float f32x4;
typedef __attribute__((ext_vector_type(8))) short sh8;

__device__ __forceinline__ float bf2f(unsigned short u){
    union { unsigned int i; float f; } v; v.i = ((unsigned)u) << 16; return v.f;
}
__device__ __forceinline__ unsigned short f2bf(float f){
    union { float f; unsigned int i; } v; v.f = f;
    unsigned int x = v.i;
    x += 0x7fff + ((x >> 16) & 1);   // RNE; inputs finite
    return (unsigned short)(x >> 16);
}

// ---------------------------------------------------------------------------
// Merged weight transform conv2..conv8:
// w [COUT][CIN][3][3] fp32 -> wT [tap][COUT][CIN] bf16 (RNE)
// ---------------------------------------------------------------------------
struct WTArgs {
    const float* src[7];
    unsigned short* hi[7];
    int cin[7];
    int start[8];
};

__global__ void wtrans_all(WTArgs a)
{
    int e = blockIdx.x * 256 + threadIdx.x;
    if (e >= a.start[7]) return;
    int l = 0;
    while (e >= a.start[l + 1]) l++;
    int eL = e - a.start[l];
    int CIN = a.cin[l];
    int tap = eL % 9, rest = eL / 9;
    int ci = rest % CIN, co = rest / CIN;
    int COUT = (a.start[l + 1] - a.start[l]) / (9 * CIN);
    a.hi[l][(tap * COUT + co) * CIN + ci] = f2bf(a.src[l][eL]);
}

// ---------------------------------------------------------------------------
// conv1: Cin=2 fp32 direct conv + BN + ReLU -> NHWC bf16 (full batch)
// ---------------------------------------------------------------------------
__global__ __launch_bounds__(256) void conv1_kernel(
    const float* __restrict__ in, const float* __restrict__ w,
    const float* __restrict__ cb, const float* __restrict__ sc,
    const float* __restrict__ tb, unsigned short* __restrict__ out)
{
    __shared__ float s_w[18 * 64];
    __shared__ float s_in[2][18 * 20];

    const int tid = threadIdx.x;
    const int b = blockIdx.y;
    const int tile = blockIdx.x;
    const int ty = tile >> 3, tx = tile & 7;
    const int y0 = ty * 16, x0 = tx * 16;

    for (int idx = tid; idx < 1152; idx += 256) {
        int co = idx & 63, kk2 = idx >> 6;
        s_w[kk2 * 64 + co] = w[co * 18 + kk2];
    }
    for (int idx = tid; idx < 2 * 324; idx += 256) {
        int ci = idx / 324, rem = idx % 324;
        int r = rem / 18, c = rem % 18;
        int gy = y0 + r - 1, gx = x0 + c - 1;
        float v = 0.f;
        if (gy >= 0 && gy < 128 && gx >= 0 && gx < 128)
            v = in[((size_t)(b * 2 + ci) * 128 + gy) * 128 + gx];
        s_in[ci][r * 20 + c] = v;
    }
    __syncthreads();

    const int cog = tid >> 5;
    const int slot = tid & 31;
    const int sy = slot >> 2, sx = slot & 3;

    float p[2][4][6];
#pragma unroll
    for (int ci = 0; ci < 2; ci++)
#pragma unroll
        for (int r = 0; r < 4; r++)
#pragma unroll
            for (int c = 0; c < 6; c++)
                p[ci][r][c] = s_in[ci][(2 * sy + r) * 20 + 4 * sx + c];

    float acc[2][4][8];
#pragma unroll
    for (int r = 0; r < 2; r++)
#pragma unroll
        for (int c = 0; c < 4; c++)
#pragma unroll
            for (int o = 0; o < 8; o++) acc[r][c][o] = 0.f;

#pragma unroll
    for (int kk2 = 0; kk2 < 18; kk2++) {
        const int ci = kk2 / 9, k = kk2 % 9;
        const int ky = k / 3, kx = k % 3;
        float wv[8];
#pragma unroll
        for (int q = 0; q < 2; q++) {
            f32x4 w4 = *(const f32x4*)(&s_w[kk2 * 64 + cog * 8 + q * 4]);
#pragma unroll
            for (int z = 0; z < 4; z++) wv[q * 4 + z] = w4[z];
        }
#pragma unroll
        for (int r = 0; r < 2; r++)
#pragma unroll
            for (int c = 0; c < 4; c++) {
                float pv = p[ci][r + ky][c + kx];
#pragma unroll
                for (int o = 0; o < 8; o++) acc[r][c][o] += pv * wv[o];
            }
    }

    float bb[8], ss[8], tt[8];
#pragma unroll
    for (int o = 0; o < 8; o++) { bb[o] = cb[cog*8+o]; ss[o] = sc[cog*8+o]; tt[o] = tb[cog*8+o]; }
#pragma unroll
    for (int r = 0; r < 2; r++)
#pragma unroll
        for (int c = 0; c < 4; c++) {
            unsigned short ov[8];
#pragma unroll
            for (int o = 0; o < 8; o++)
                ov[o] = f2bf(fmaxf((acc[r][c][o] + bb[o]) * ss[o] + tt[o], 0.f));
            int py = y0 + 2 * sy + r, px = x0 + 4 * sx + c;
            *(sh8*)(out + ((size_t)(b * 128 + py) * 128 + px) * 64 + cog * 8) = *(sh8*)ov;
        }
}

// ---------------------------------------------------------------------------
// MFMA implicit-GEMM conv3x3 + BN + ReLU (+ fused 2x2 maxpool), v9:
// round-10 v6 flow EXACTLY (plain __syncthreads per tap, setprio, same
// epilogues) with ALL LDS/global addresses hoisted to per-thread bases +
// compile-time offsets so ds_read/global_load fold into offset immediates:
//   aF:  lds_A[aBase[pf] + ((ky*HALW+kx)*ST + kk*32)]      (tOff constexpr)
//   bF:  lds_W[bi*4096 + bOff[cf][kk]]                     (bi constexpr)
//   W:   wgt[tap*COUT*CIN + c*64 + wOfs[q]]                (uniform part SALU)
// ---------------------------------------------------------------------------
template<int CIN, int COUT, int HI, int WI, int POOL, int TW, int NPG, int KSPLIT>
__global__ __launch_bounds__(NPG * 128, 4) void conv_mfma(
    const unsigned short* __restrict__ in,
    const unsigned short* __restrict__ wgt,
    const float* __restrict__ cb, const float* __restrict__ sc,
    const float* __restrict__ tb, void* __restrict__ outv)
{
    constexpr int THREADS = NPG * 128;
    constexpr int TH = (TW == 32) ? 2 * NPG : 4 * NPG;
    constexpr int HALW = TW + 2, HALH = TH + 2;
    constexpr int NPIX = HALW * HALH;
    constexpr int CHUNKS = CIN / 64;
    constexpr int TILESX = WI / TW;
    constexpr int HO = HI / POOL, WO = WI / POOL;
    constexpr int ST = 68;
    constexpr int NCOG = COUT / 64;
    constexpr int GPT = 512 / THREADS;
    constexpr int LOG_NPG = (NPG == 4) ? 2 : 1;

    __shared__ __align__(16) unsigned short lds_A[NPIX * ST];
    __shared__ __align__(16) unsigned short lds_W[2 * 4096];

    const int tid = threadIdx.x;
    const int lane = tid & 63;
    const int i = lane & 15, j = lane >> 4;
    const int wv = tid >> 6;
    const int pg = wv & (NPG - 1);
    const int cg = wv >> LOG_NPG;
    const int tile = blockIdx.x;
    const int ty = tile / TILESX, tx = tile % TILESX;
    const int y0 = ty * TH, x0 = tx * TW;
    const int cogrp = (NCOG == 1) ? 0 : (blockIdx.y & (NCOG - 1));
    const int kc = (KSPLIT == 2) ? (blockIdx.y >> (NCOG == 2 ? 1 : 0)) : 0;
    const int coBase = cogrp * 64;
    const int b = blockIdx.z;

    // ---- hoisted per-thread address bases (element offsets) ----
    int aBase[4];
#pragma unroll
    for (int pf = 0; pf < 4; pf++) {
        const int nf = pg * 4 + pf;
        int row, col;
        if (TW == 32) { row = nf >> 1; col = (nf & 1) * 16 + i; }
        else          { row = nf;      col = i; }
        aBase[pf] = (row * HALW + col) * ST + j * 8;
    }
    int bOff[2][2];
#pragma unroll
    for (int cf = 0; cf < 2; cf++) {
        const int co_l = cg * 32 + cf * 16 + i;
#pragma unroll
        for (int kk = 0; kk < 2; kk++) {
            const int phys = ((kk << 2) | j) ^ (co_l & 7);
            bOff[cf][kk] = co_l * 64 + phys * 8;
        }
    }
    size_t wOfs[GPT];
#pragma unroll
    for (int q = 0; q < GPT; q++) {
        int g = tid + q * THREADS;
        int slot = g & 7;
        int co = g >> 3;
        int gl = slot ^ (co & 7);
        wOfs[q] = (size_t)(coBase + co) * CIN + gl * 8;
    }

    f32x4 acc[4][2];
#pragma unroll
    for (int pf = 0; pf < 4; pf++)
#pragma unroll
        for (int cf = 0; cf < 2; cf++) acc[pf][cf] = (f32x4){0.f, 0.f, 0.f, 0.f};

    sh8 rw[GPT];

    constexpr int NCH = (KSPLIT == 2) ? 1 : CHUNKS;
    for (int cc = 0; cc < NCH; cc++) {
        const int c = (KSPLIT == 2) ? kc : cc;
        if (cc) __syncthreads();

        // ---- stage A halo: NPIX px x 64 cin, zero-padded ----
        for (int u = tid; u < NPIX * 8; u += THREADS) {
            int hp = u >> 3, c16 = u & 7;
            int hy = hp / HALW, hx = hp % HALW;
            int gy = y0 + hy - 1, gx = x0 + hx - 1;
            sh8 v = (sh8){0,0,0,0,0,0,0,0};
            if (gy >= 0 && gy < HI && gx >= 0 && gx < WI)
                v = *(const sh8*)(in + ((size_t)(b * HI + gy) * WI + gx) * CIN + c * 64 + c16 * 8);
            *(sh8*)(&lds_A[hp * ST + c16 * 8]) = v;
        }

        const unsigned short* wChunk = wgt + c * 64;   // + tap*COUT*CIN + wOfs[q]

        auto LOADW = [&](int tap) {
#pragma unroll
            for (int q = 0; q < GPT; q++)
                rw[q] = *(const sh8*)(wChunk + (size_t)tap * (COUT * CIN) + wOfs[q]);
        };
        auto WRITEW = [&](int bi) {
#pragma unroll
            for (int q = 0; q < GPT; q++)
                *(sh8*)(&lds_W[bi * 4096 + (tid + q * THREADS) * 8]) = rw[q];
        };

        LOADW(0); WRITEW(0);
        __syncthreads();

#pragma unroll
        for (int tap = 0; tap < 9; tap++) {
            if (tap < 8) LOADW(tap + 1);            // global prefetch under MFMA
            const int ky = tap / 3, kx = tap % 3;   // constexpr after unroll
            const int tOff = (ky * HALW + kx) * ST;
            const int bi = tap & 1;
#pragma unroll
            for (int kk = 0; kk < 2; kk++) {
                sh8 aF[4], bF[2];
#pragma unroll
                for (int pf = 0; pf < 4; pf++)
                    aF[pf] = *(const sh8*)(&lds_A[aBase[pf] + tOff + kk * 32]);
#pragma unroll
                for (int cf = 0; cf < 2; cf++)
                    bF[cf] = *(const sh8*)(&lds_W[bi * 4096 + bOff[cf][kk]]);
                __builtin_amdgcn_s_setprio(1);
#pragma unroll
                for (int pf = 0; pf < 4; pf++)
#pragma unroll
                    for (int cf = 0; cf < 2; cf++)
                        acc[pf][cf] = __builtin_amdgcn_mfma_f32_16x16x32_bf16(
                            aF[pf], bF[cf], acc[pf][cf], 0, 0, 0);
                __builtin_amdgcn_s_setprio(0);
            }
            if (tap < 8) { WRITEW((tap + 1) & 1); __syncthreads(); }
        }
    }

    if constexpr (KSPLIT == 2) {
        float* po = (float*)outv + (size_t)kc * 64 * HO * WO * COUT;
#pragma unroll
        for (int cf = 0; cf < 2; cf++) {
            const int co = coBase + cg * 32 + cf * 16 + i;
#pragma unroll
            for (int pf = 0; pf < 4; pf++) {
                const int nf = pg * 4 + pf;
                int py, pxb;
                if (TW == 32) { py = nf >> 1; pxb = (nf & 1) * 16; }
                else          { py = nf;      pxb = 0; }
#pragma unroll
                for (int r = 0; r < 4; r++)
                    po[((size_t)(b * HO + y0 + py) * WO + x0 + pxb + j * 4 + r) * COUT + co] =
                        acc[pf][cf][r];
            }
        }
        return;
    }

    unsigned short* out = (unsigned short*)outv;
#pragma unroll
    for (int cf = 0; cf < 2; cf++) {
        const int co = coBase + cg * 32 + cf * 16 + i;
        const float b3 = cb[co], s3 = sc[co], t3 = tb[co];
        if (POOL == 1) {
#pragma unroll
            for (int pf = 0; pf < 4; pf++) {
                const int nf = pg * 4 + pf;
                int py, pxb;
                if (TW == 32) { py = nf >> 1; pxb = (nf & 1) * 16; }
                else          { py = nf;      pxb = 0; }
#pragma unroll
                for (int r = 0; r < 4; r++) {
                    float v = fmaxf((acc[pf][cf][r] + b3) * s3 + t3, 0.f);
                    out[((size_t)(b * HO + y0 + py) * WO + x0 + pxb + j * 4 + r) * COUT + co] = f2bf(v);
                }
            }
        } else if constexpr (POOL == 2 && TW == 32) {
#pragma unroll
            for (int h = 0; h < 2; h++) {
                const int pfA = h, pfB = 2 + h;
#pragma unroll
                for (int r2 = 0; r2 < 2; r2++) {
                    float vA0 = fmaxf((acc[pfA][cf][2*r2]   + b3) * s3 + t3, 0.f);
                    float vA1 = fmaxf((acc[pfA][cf][2*r2+1] + b3) * s3 + t3, 0.f);
                    float vB0 = fmaxf((acc[pfB][cf][2*r2]   + b3) * s3 + t3, 0.f);
                    float vB1 = fmaxf((acc[pfB][cf][2*r2+1] + b3) * s3 + t3, 0.f);
                    float v = fmaxf(fmaxf(vA0, vA1), fmaxf(vB0, vB1));
                    int pox = (x0 >> 1) + h * 8 + j * 2 + r2;
                    int poy = (y0 >> 1) + pg;
                    out[((size_t)(b * HO + poy) * WO + pox) * COUT + co] = f2bf(v);
                }
            }
        }
    }
}

// ---------------------------------------------------------------------------
// split-K combine
// ---------------------------------------------------------------------------
__global__ void combine_k(const float* __restrict__ part, const float* __restrict__ cb,
                          const float* __restrict__ sc, const float* __restrict__ tb,
                          unsigned short* __restrict__ out)
{
    int e = blockIdx.x * 256 + threadIdx.x;
    int co = e & 127;
    float v = part[e] + part[e + 2097152];
    out[e] = f2bf(fmaxf((v + cb[co]) * sc[co] + tb[co], 0.f));
}

// ---------------------------------------------------------------------------
// 6x6/6 maxpool
// ---------------------------------------------------------------------------
__global__ void pool6_kernel(const unsigned short* __restrict__ in, float* __restrict__ out)
{
    int t = blockIdx.x * 256 + threadIdx.x;
    if (t >= 64 * 128 * 4) return;
    int ox = t & 1, oy = (t >> 1) & 1, c = (t >> 2) & 127, b = t >> 9;
    const unsigned short* p = in + ((size_t)(b * 16 + oy * 6) * 16 + ox * 6) * 128 + c;
    float m = -INFINITY;
#pragma unroll
    for (int r = 0; r < 6; r++)
#pragma unroll
        for (int cc = 0; cc < 6; cc++) m = fmaxf(m, bf2f(p[(r * 16 + cc) * 128]));
    out[(size_t)b * 512 + c * 4 + oy * 2 + ox] = m;
}

// ---------------------------------------------------------------------------
// FC1 / FC2
// ---------------------------------------------------------------------------
__global__ void fc1_kernel(const float* __restrict__ flat, const float* __restrict__ fcw,
                           const float* __restrict__ fcb, float* __restrict__ out1)
{
    int b = blockIdx.y;
    int jj = blockIdx.x * 256 + threadIdx.x;
    const f32x4* f = (const f32x4*)(flat + (size_t)b * 512);
    const f32x4* w = (const f32x4*)(fcw + (size_t)jj * 512);
    float s = fcb[jj];
    for (int k = 0; k < 128; k++) {
        f32x4 a = f[k], ww = w[k];
        s += a[0]*ww[0] + a[1]*ww[1] + a[2]*ww[2] + a[3]*ww[3];
    }
    out1[(size_t)b * 1024 + jj] = fmaxf(s, 0.f);
}

__global__ void fc2_kernel(const float* __restrict__ out1, const float* __restrict__ f1w,
                           const float* __restrict__ f1b, float* __restrict__ h4pt)
{
    int b = blockIdx.x;
    int o = threadIdx.x >> 5, s2 = threadIdx.x & 31;
    const float* pa = out1 + (size_t)b * 1024;
    const float* pw = f1w + (size_t)o * 1024;
    float s = 0.f;
    for (int k = s2; k < 1024; k += 32) s += pa[k] * pw[k];
#pragma unroll
    for (int m = 16; m; m >>= 1) s += __shfl_xor(s, m);
    if (s2 == 0) h4pt[b * 8 + o] = s + f1b[o];
}

// ---------------------------------------------------------------------------
// DLT v2: row-per-lane fp64 Gauss elimination with partial pivoting (proven).
// ---------------------------------------------------------------------------
__global__ __launch_bounds__(512) void dlt_kernel(
    const float* __restrict__ h4pt, const float* __restrict__ corner,
    double* __restrict__ hinv)
{
    const int t = threadIdx.x;
    const int lane = t & 63;
    const int r = lane & 7;
    const int base = lane & ~7;
    const int b = (t >> 6) * 8 + (lane >> 3);

    const int jq = r >> 1;
    const double U  = (double)corner[b * 8 + 2 * jq];
    const double V  = (double)corner[b * 8 + 2 * jq + 1];
    const double Ud = U + (double)h4pt[b * 8 + 2 * jq];
    const double Vd = V + (double)h4pt[b * 8 + 2 * jq + 1];

    double Ar[9];
    if ((r & 1) == 0) {
        Ar[0] = 0;  Ar[1] = 0;  Ar[2] = 0;
        Ar[3] = -U; Ar[4] = V;  Ar[5] = -1;
        Ar[6] = Vd * U; Ar[7] = Vd * V; Ar[8] = -Vd;
    } else {
        Ar[0] = U;  Ar[1] = V;  Ar[2] = 1;
        Ar[3] = 0;  Ar[4] = 0;  Ar[5] = 0;
        Ar[6] = -Ud * U; Ar[7] = -Ud * V; Ar[8] = Ud;
    }

#pragma unroll
    for (int col = 0; col < 8; col++) {
        double val = (r >= col) ? fabs(Ar[col]) : -1.0;
        int idx = r;
#pragma unroll
        for (int m = 1; m < 8; m <<= 1) {
            double ov = __shfl_xor(val, m, 64);
            int oi = __shfl_xor(idx, m, 64);
            if (ov > val || (ov == val && oi < idx)) { val = ov; idx = oi; }
        }
        const int src = (r == col) ? idx : (r == idx) ? col : r;
#pragma unroll
        for (int k = 0; k < 9; k++) Ar[k] = __shfl(Ar[k], base + src, 64);
        double pr[9];
#pragma unroll
        for (int k = 0; k < 9; k++) pr[k] = __shfl(Ar[k], base + col, 64);
        if (r > col) {
            const double f = Ar[col] / pr[col];
#pragma unroll
            for (int k = 0; k < 9; k++) Ar[k] -= f * pr[k];
        }
    }

    double h[9];
    h[8] = 1.0;
#pragma unroll
    for (int col = 7; col >= 0; col--) {
        const double xc = __shfl(Ar[8] / Ar[col], base + col, 64);
        h[col] = xc;
        if (r < col) Ar[8] -= Ar[col] * xc;
    }

    const double a = h[0], bb = h[1], cq = h[2], d = h[3], e = h[4],
                 f = h[5], g = h[6], hh = h[7], iq = h[8];
    const double C0 = e * iq - f * hh, C1 = cq * hh - bb * iq, C2 = bb * f - cq * e;
    const double C3 = f * g - d * iq,  C4 = a * iq - cq * g,   C5 = cq * d - a * f;
    const double C6 = d * hh - e * g,  C7 = bb * g - a * hh,   C8 = a * e - bb * d;
    const double det = a * C0 + bb * C3 + cq * C6;
    const double idet = 1.0 / det;
    double my = (r == 0) ? C0 : (r == 1) ? C1 : (r == 2) ? C2 : (r == 3) ? C3
              : (r == 4) ? C4 : (r == 5) ? C5 : (r == 6) ? C6 : C7;
    double* o = hinv + b * 9;
    o[r] = my * idet;
    if (r == 0) o[8] = C8 * idet;
}

// ---------------------------------------------------------------------------
// Perspective warp + bilinear (coords fp64, gather fp32)
// ---------------------------------------------------------------------------
__global__ void warp_kernel(const float* __restrict__ img, const double* __restrict__ hinv,
                            float* __restrict__ out)
{
    int b = blockIdx.y;
    int pix = blockIdx.x * 256 + threadIdx.x;
    int y = pix >> 7, x = pix & 127;
    const double* h = hinv + b * 9;
    double X = (double)x, Y = (double)y;
    double p0 = h[0] * X + h[1] * Y + h[2];
    double p1 = h[3] * X + h[4] * Y + h[5];
    double p2 = h[6] * X + h[7] * Y + h[8];
    double xs = p0 / p2, ys = p1 / p2;
    double x0d = floor(xs), y0d = floor(ys);
    double wx = xs - x0d, wy = ys - y0d;
    int x0 = (int)x0d, y0 = (int)y0d;
    const float* im = img + (size_t)b * 240 * 320;
    auto gat = [&](int yi, int xi) -> double {
        bool valid = (xi >= 0) & (xi < 320) & (yi >= 0) & (yi < 240);
        int yc = yi < 0 ? 0 : (yi > 239 ? 239 : yi);
        int xc = xi < 0 ? 0 : (xi > 319 ? 319 : xi);
        double v = (double)im[yc * 320 + xc];
        return valid ? v : 0.0;
    };
    double v00 = gat(y0, x0),     v01 = gat(y0, x0 + 1);
    double v10 = gat(y0 + 1, x0), v11 = gat(y0 + 1, x0 + 1);
    double rr = v00 * (1 - wx) * (1 - wy) + v01 * wx * (1 - wy)
              + v10 * (1 - wx) * wy       + v11 * wx * wy;
    out[((size_t)b << 14) + pix] = (float)rr;
}

// ---------------------------------------------------------------------------
// launch — full-batch, no chunking.
// Layout: A1 134.2 MB | B2 33.5 MB | weights 1.25 MB | small.  Total ~170 MB.
// ---------------------------------------------------------------------------
extern "C" void kernel_launch(void* const* d_in, const int* in_sizes, int n_in,
                              void* d_out, int out_size, void* d_ws, size_t ws_size,
                              hipStream_t stream)
{
    const float* TI1     = (const float*)d_in[1];
    const float* TImgA   = (const float*)d_in[2];
    const float* TCorner = (const float*)d_in[3];
    const float* w[8], *cbp[8], *sp[8], *tp[8];
    for (int l = 0; l < 8; l++) {
        w[l]   = (const float*)d_in[4 + 4 * l];
        cbp[l] = (const float*)d_in[5 + 4 * l];
        sp[l]  = (const float*)d_in[6 + 4 * l];
        tp[l]  = (const float*)d_in[7 + 4 * l];
    }
    const float* fcw = (const float*)d_in[36];
    const float* fcb = (const float*)d_in[37];
    const float* f1w = (const float*)d_in[38];
    const float* f1b = (const float*)d_in[39];

    char* base = (char*)d_ws;
    unsigned short* A1   = (unsigned short*)(base);                   // 134,217,728 B
    unsigned short* B2   = (unsigned short*)(base + 134217728);       // 33,554,432 B
    unsigned short* whiA = (unsigned short*)(base + 167772160);       // 1,253,376 B
    float*  feat = (float*) (base + 167772160 + 1253376);
    float*  fc1o = feat + 64 * 512;
    float*  h4pt = fc1o + 64 * 1024;
    double* hinv = (double*)(h4pt + 512);
    float*  outp = (float*)d_out;

    // conv7/8 split-K sub-regions (A1 free as scratch after conv5)
    float*          part7 = (float*)A1;                               // 16.8 MB
    unsigned short* c7out = (unsigned short*)(base + 134217728 + 8388608);   // B2+8MB
    float*          part8 = (float*)A1;
    unsigned short* c8out = (unsigned short*)(base + 134217728 + 16777216);  // B2+16MB

    const int CINS[7]  = {64, 64, 64, 64, 128, 128, 128};
    const int COUTS[7] = {64, 64, 64, 128, 128, 128, 128};
    int wofs[8]; wofs[0] = 0;
    for (int l = 0; l < 7; l++) wofs[l + 1] = wofs[l] + 9 * COUTS[l] * CINS[l];

    WTArgs wa;
    for (int l = 0; l < 7; l++) {
        wa.src[l] = w[l + 1];
        wa.hi[l] = whiA + wofs[l];
        wa.cin[l] = CINS[l];
        wa.start[l] = wofs[l];
    }
    wa.start[7] = wofs[7];
    wtrans_all<<<(wofs[7] + 255) / 256, 256, 0, stream>>>(wa);

    // conv1 full batch -> A1 ; conv2 full batch -> B2
    conv1_kernel<<<dim3(64, 64), 256, 0, stream>>>(
        TI1, w[0], cbp[0], sp[0], tp[0], A1);
    conv_mfma<64, 64, 128, 128, 2, 32, 4, 1><<<dim3(64, 1, 64), 512, 0, stream>>>(
        A1, whiA + wofs[0], cbp[1], sp[1], tp[1], B2);
    // conv3..conv6, ping-pong B2 <-> A1
    conv_mfma<64, 64, 64, 64, 1, 32, 4, 1><<<dim3(16, 1, 64), 512, 0, stream>>>(
        B2, whiA + wofs[1], cbp[2], sp[2], tp[2], A1);
    conv_mfma<64, 64, 64, 64, 2, 32, 4, 1><<<dim3(16, 1, 64), 512, 0, stream>>>(
        A1, whiA + wofs[2], cbp[3], sp[3], tp[3], B2);
    conv_mfma<64, 128, 32, 32, 1, 32, 4, 1><<<dim3(4, 2, 64), 512, 0, stream>>>(
        B2, whiA + wofs[3], cbp[4], sp[4], tp[4], A1);
    conv_mfma<128, 128, 32, 32, 2, 32, 4, 1><<<dim3(4, 2, 64), 512, 0, stream>>>(
        A1, whiA + wofs[4], cbp[5], sp[5], tp[5], B2);
    // conv7/8: split-K over cin halves -> fp32 partials in A1 -> combine
    conv_mfma<128, 128, 16, 16, 1, 16, 2, 2><<<dim3(2, 4, 64), 256, 0, stream>>>(
        B2, whiA + wofs[5], cbp[6], sp[6], tp[6], part7);
    combine_k<<<8192, 256, 0, stream>>>(part7, cbp[6], sp[6], tp[6], c7out);
    conv_mfma<128, 128, 16, 16, 1, 16, 2, 2><<<dim3(2, 4, 64), 256, 0, stream>>>(
        c7out, whiA + wofs[6], cbp[7], sp[7], tp[7], part8);
    combine_k<<<8192, 256, 0, stream>>>(part8, cbp[7], sp[7], tp[7], c8out);

    pool6_kernel<<<128, 256, 0, stream>>>(c8out, feat);
    fc1_kernel<<<dim3(4, 64), 256, 0, stream>>>(feat, fcw, fcb, fc1o);
    fc2_kernel<<<64, 256, 0, stream>>>(fc1o, f1w, f1b, h4pt);
    dlt_kernel<<<1, 512, 0, stream>>>(h4pt, TCorner, hinv);
    warp_kernel<<<dim3(64, 64), 256, 0, stream>>>(TImgA, hinv, outp);
}